// Round 1
// baseline (635.717 us; speedup 1.0000x reference)
//
#include <hip/hip_runtime.h>
#include <math.h>

// ---------------------------------------------------------------------------
// QuantumInspiredLayer, all-f32 correctness-first round.
//   K0a/K0b: G = W2 W2^T (partials over 16 k-slices, then reduce)  [for LN stats]
//   K0c:     wbar[a]=sum_j W2[a][j], hb[a]=sum_j W2[a][j] b2[j], sumb, sum b2^2
//   K1:      q = tanh(x @ W1[:, :64] + b1[:64]); per-row 32-qubit circuit -> feats
//            (feats[:, :128] only involves qubits 0..31 => W1 cols 64..127 dead)
//   K2:      per 64-row block: LN stats analytically (mu, var from G/wbar/hb),
//            then single-pass out = LN(feats@W2 + b2)*gamma + beta + x
// ws layout (floats): feats(2097152) | G(16384) | Gpart(262144) | wbar(128) |
//                     hb(128) | scal(8)   => ~9.5 MB
// ---------------------------------------------------------------------------

#define B_ROWS 16384
#define D_DIM  4096
#define LN_EPS 1e-5f

#define OFF_FEATS 0
#define N_FEATS   (B_ROWS * 128)
#define OFF_G     (OFF_FEATS + N_FEATS)
#define N_G       (128 * 128)
#define OFF_GPART (OFF_G + N_G)
#define N_GPART   (16 * 128 * 128)
#define OFF_WBAR  (OFF_GPART + N_GPART)
#define OFF_HB    (OFF_WBAR + 128)
#define OFF_SCAL  (OFF_HB + 128)

#define FMA16(ACC, AV, BV)                                   \
  ACC[0][0] = fmaf(AV.x, BV.x, ACC[0][0]);                   \
  ACC[0][1] = fmaf(AV.x, BV.y, ACC[0][1]);                   \
  ACC[0][2] = fmaf(AV.x, BV.z, ACC[0][2]);                   \
  ACC[0][3] = fmaf(AV.x, BV.w, ACC[0][3]);                   \
  ACC[1][0] = fmaf(AV.y, BV.x, ACC[1][0]);                   \
  ACC[1][1] = fmaf(AV.y, BV.y, ACC[1][1]);                   \
  ACC[1][2] = fmaf(AV.y, BV.z, ACC[1][2]);                   \
  ACC[1][3] = fmaf(AV.y, BV.w, ACC[1][3]);                   \
  ACC[2][0] = fmaf(AV.z, BV.x, ACC[2][0]);                   \
  ACC[2][1] = fmaf(AV.z, BV.y, ACC[2][1]);                   \
  ACC[2][2] = fmaf(AV.z, BV.z, ACC[2][2]);                   \
  ACC[2][3] = fmaf(AV.z, BV.w, ACC[2][3]);                   \
  ACC[3][0] = fmaf(AV.w, BV.x, ACC[3][0]);                   \
  ACC[3][1] = fmaf(AV.w, BV.y, ACC[3][1]);                   \
  ACC[3][2] = fmaf(AV.w, BV.z, ACC[3][2]);                   \
  ACC[3][3] = fmaf(AV.w, BV.w, ACC[3][3]);

// ---------------- K0a: Gpart[kp][a][b] = sum_{k in kp-slice} W2[a][k]W2[b][k]
__global__ __launch_bounds__(256) void k0a(const float* __restrict__ W2,
                                           float* __restrict__ gpart) {
  __shared__ float wbt[32][132];  // wbt[k][row-of-W2]
  const int tid = threadIdx.x;
  const int ac = blockIdx.x & 3;        // a-chunk 0..3 (32 rows each)
  const int kp = blockIdx.x >> 2;       // k-slice 0..15 (256 k each)
  const int kbase = kp * 256;
  const int ag = tid >> 5, a0 = ag * 4; // 8 groups x 4 rows = 32
  const int bg = tid & 31, b0 = bg * 4; // 32 groups x 4 cols = 128
  const int sb = tid >> 1;              // staging: W2 row 0..127
  const int sk = (tid & 1) * 16;        // staging: k offset 0/16
  float acc[4][4] = {};
  for (int sub = 0; sub < 8; ++sub) {
    const int k0 = kbase + sub * 32;
    const float* wp = W2 + (size_t)sb * D_DIM + k0 + sk;
#pragma unroll
    for (int j4 = 0; j4 < 4; ++j4) {
      float4 v = *(const float4*)(wp + j4 * 4);
      wbt[sk + j4 * 4 + 0][sb] = v.x;
      wbt[sk + j4 * 4 + 1][sb] = v.y;
      wbt[sk + j4 * 4 + 2][sb] = v.z;
      wbt[sk + j4 * 4 + 3][sb] = v.w;
    }
    __syncthreads();
#pragma unroll 8
    for (int k = 0; k < 32; ++k) {
      float4 av = *(const float4*)&wbt[k][ac * 32 + a0];
      float4 bv = *(const float4*)&wbt[k][b0];
      FMA16(acc, av, bv)
    }
    __syncthreads();
  }
  float* gp = gpart + (size_t)kp * 16384 + (size_t)(ac * 32 + a0) * 128 + b0;
#pragma unroll
  for (int i = 0; i < 4; ++i) {
    float4 v;
    v.x = acc[i][0]; v.y = acc[i][1]; v.z = acc[i][2]; v.w = acc[i][3];
    *(float4*)(gp + (size_t)i * 128) = v;
  }
}

// ---------------- K0b: reduce 16 partials -> G
__global__ __launch_bounds__(256) void k0b(const float* __restrict__ gpart,
                                           float* __restrict__ G) {
  const int e = blockIdx.x * 256 + threadIdx.x;  // 64 blocks * 256 = 16384
  float s = 0.f;
#pragma unroll
  for (int p = 0; p < 16; ++p) s += gpart[(size_t)p * 16384 + e];
  G[e] = s;
}

// ---------------- K0c: wbar, hb, sumb, sum b2^2
__global__ __launch_bounds__(256) void k0c(const float* __restrict__ W2,
                                           const float* __restrict__ b2,
                                           float* __restrict__ wbar,
                                           float* __restrict__ hb,
                                           float* __restrict__ scal) {
  __shared__ float r1[256], r2[256];
  const int a = blockIdx.x, t = threadIdx.x;
  float s1 = 0.f, s2 = 0.f;
  if (a < 128) {
    const float* wp = W2 + (size_t)a * D_DIM;
    for (int j = t; j < D_DIM; j += 256) { float w = wp[j]; s1 += w; s2 = fmaf(w, b2[j], s2); }
  } else {
    for (int j = t; j < D_DIM; j += 256) { float b = b2[j]; s1 += b; s2 = fmaf(b, b, s2); }
  }
  r1[t] = s1; r2[t] = s2;
  __syncthreads();
  for (int s = 128; s > 0; s >>= 1) {
    if (t < s) { r1[t] += r1[t + s]; r2[t] += r2[t + s]; }
    __syncthreads();
  }
  if (t == 0) {
    if (a < 128) { wbar[a] = r1[0]; hb[a] = r2[0]; }
    else         { scal[0] = r1[0]; scal[1] = r2[0]; }
  }
}

// ---------------- K1: GEMM1 (f32, cols 0..63 only) + tanh + quantum circuit
__global__ __launch_bounds__(256) void k1(const float* __restrict__ x,
                                          const float* __restrict__ W1,
                                          const float* __restrict__ b1,
                                          float* __restrict__ feats) {
  __shared__ float xs[64][68];   // xs[k][row] (transposed x tile)
  __shared__ float ws1[64][68];  // ws1[k][col]
  const int tid = threadIdx.x;
  const size_t row0 = (size_t)blockIdx.x * 64;
  const int rg = tid >> 4, cg = tid & 15;
  const int r0 = rg * 4, c0 = cg * 4;
  const int sr = tid >> 2;             // staging row / k-row 0..63
  const int sq = (tid & 3) * 16;       // staging quad offset
  float acc[4][4] = {};
  for (int k0 = 0; k0 < D_DIM; k0 += 64) {
    const float* xp = x + (row0 + sr) * D_DIM + k0 + sq;
#pragma unroll
    for (int j4 = 0; j4 < 4; ++j4) {
      float4 v = *(const float4*)(xp + j4 * 4);
      xs[sq + j4 * 4 + 0][sr] = v.x;
      xs[sq + j4 * 4 + 1][sr] = v.y;
      xs[sq + j4 * 4 + 2][sr] = v.z;
      xs[sq + j4 * 4 + 3][sr] = v.w;
    }
    const float* wp = W1 + (size_t)(k0 + sr) * 128 + sq;  // only cols 0..63 used
#pragma unroll
    for (int j4 = 0; j4 < 4; ++j4)
      *(float4*)&ws1[sr][sq + j4 * 4] = *(const float4*)(wp + j4 * 4);
    __syncthreads();
#pragma unroll 8
    for (int k = 0; k < 64; ++k) {
      float4 xv = *(const float4*)&xs[k][r0];
      float4 wv = *(const float4*)&ws1[k][c0];
      FMA16(acc, xv, wv)
    }
    __syncthreads();
  }
  // q = tanh(acc + b1) -> reuse xs as q[row][col]
#pragma unroll
  for (int i = 0; i < 4; ++i)
#pragma unroll
    for (int j = 0; j < 4; ++j)
      xs[r0 + i][c0 + j] = tanhf(acc[i][j] + b1[c0 + j]);
  __syncthreads();
  if (tid < 64) {
    const int r = tid;
    float* frow = feats + (row0 + r) * 128;
    const float PI_F = 3.14159274101257324f;     // f32(np.pi)
    const float IS2  = 0.707106769084930420f;    // f32(1/sqrt(2))
    bool swp = false;
    for (int j = 0; j < 32; ++j) {
      float th = xs[r][2 * j] * PI_F;
      float ph = xs[r][2 * j + 1] * PI_F;
      float hf = 0.5f * th;
      float chf = cosf(hf), shf = sinf(hf);
      float cp = cosf(ph), sp = sinf(ph);
      float ar = chf, ai = 0.0f;
      float br = shf * cp, bi = shf * sp;
      if ((j & 1) == 0) {  // Hadamard on even qubits
        float t1r = (ar + br) * IS2, t1i = (ai + bi) * IS2;
        float t2r = (ar - br) * IS2, t2i = (ai - bi) * IS2;
        ar = t1r; ai = t1i; br = t2r; bi = t2i;
      }
      if (swp) { float t = ar; ar = br; br = t; t = ai; ai = bi; bi = t; }
      float4 o; o.x = ar; o.y = ai; o.z = br; o.w = bi;
      *(float4*)(frow + 4 * j) = o;
      swp = sqrtf(fmaf(br, br, bi * bi)) > 0.5f;  // |beta| > 0.5
    }
  }
}

// ---------------- K2: stats (analytic) + GEMM2 + LN + residual, single pass
__global__ __launch_bounds__(256) void k2(const float* __restrict__ feats,
                                          const float* __restrict__ W2,
                                          const float* __restrict__ b2,
                                          const float* __restrict__ gam,
                                          const float* __restrict__ bet,
                                          const float* __restrict__ x,
                                          const float* __restrict__ G,
                                          const float* __restrict__ wbar,
                                          const float* __restrict__ hb,
                                          const float* __restrict__ scal,
                                          float* __restrict__ out) {
  __shared__ float ft[128][68];  // ft[k][row]  (feats transposed)
  __shared__ float wt[128][68];  // wt[k][col]  (W2 tile; reused as G buffer)
  __shared__ float mu_s[64], inv_s[64];
  __shared__ float e2red[64][4];
  const int tid = threadIdx.x;
  const size_t row0 = (size_t)blockIdx.x * 64;
  {  // load feats rows (transposed)
    const int rl = tid >> 2;
    const int kq = (tid & 3) * 32;
    const float* fp = feats + (row0 + rl) * 128 + kq;
#pragma unroll
    for (int j4 = 0; j4 < 8; ++j4) {
      float4 v = *(const float4*)(fp + j4 * 4);
      ft[kq + j4 * 4 + 0][rl] = v.x;
      ft[kq + j4 * 4 + 1][rl] = v.y;
      ft[kq + j4 * 4 + 2][rl] = v.z;
      ft[kq + j4 * 4 + 3][rl] = v.w;
    }
  }
  __syncthreads();
  // ---- stats: Sum out^2 = f^T G f + 2 f.hb + Sum b2^2 ; mu = (f.wbar + sumb)/D
  {
    float* gbuf = &wt[0][0];  // [32][128] chunk of G
    const int r = tid >> 2;   // row 0..63
    const int p = tid & 3;    // b-quarter
    float e2p = 0.f, mup = 0.f, hbp = 0.f;
    for (int ch = 0; ch < 4; ++ch) {
      __syncthreads();
      {
        const int al = tid >> 3;
        const int bo = (tid & 7) * 16;
        const float* gp = G + (size_t)(ch * 32 + al) * 128 + bo;
#pragma unroll
        for (int j4 = 0; j4 < 4; ++j4)
          *(float4*)(gbuf + al * 128 + bo + j4 * 4) = *(const float4*)(gp + j4 * 4);
      }
      __syncthreads();
      float vacc[32];
#pragma unroll
      for (int i = 0; i < 32; ++i) vacc[i] = 0.f;
      for (int al = 0; al < 32; ++al) {
        const int a = ch * 32 + al;
        const float fa = ft[a][r];
        const float* grow = gbuf + al * 128 + p * 32;
#pragma unroll
        for (int t8 = 0; t8 < 8; ++t8) {  // static indices only (no spill)
          float4 gv = *(const float4*)(grow + t8 * 4);
          vacc[t8 * 4 + 0] = fmaf(fa, gv.x, vacc[t8 * 4 + 0]);
          vacc[t8 * 4 + 1] = fmaf(fa, gv.y, vacc[t8 * 4 + 1]);
          vacc[t8 * 4 + 2] = fmaf(fa, gv.z, vacc[t8 * 4 + 2]);
          vacc[t8 * 4 + 3] = fmaf(fa, gv.w, vacc[t8 * 4 + 3]);
        }
        if (p == 0) { mup = fmaf(fa, wbar[a], mup); hbp = fmaf(fa, hb[a], hbp); }
      }
#pragma unroll
      for (int bl = 0; bl < 32; ++bl)
        e2p = fmaf(vacc[bl], ft[p * 32 + bl][r], e2p);
    }
    e2red[r][p] = e2p;
    __syncthreads();
    if (p == 0) {
      float e2 = e2red[r][0] + e2red[r][1] + e2red[r][2] + e2red[r][3];
      e2 = fmaf(2.0f, hbp, e2) + scal[1];
      const float mu = (mup + scal[0]) * (1.0f / D_DIM);
      const float var = e2 * (1.0f / D_DIM) - mu * mu;
      mu_s[r] = mu;
      inv_s[r] = 1.0f / sqrtf(var + LN_EPS);
    }
  }
  // ---- GEMM2 + LN + residual
  const int rg = tid >> 4, cg = tid & 15;
  const int r0 = rg * 4, c0 = cg * 4;
  const int sk = tid >> 1;           // staging k-row 0..127
  const int sc = (tid & 1) * 32;     // staging col offset
  for (int cc = 0; cc < D_DIM; cc += 64) {
    __syncthreads();
    const float* wp = W2 + (size_t)sk * D_DIM + cc + sc;
#pragma unroll
    for (int j4 = 0; j4 < 8; ++j4)
      *(float4*)&wt[sk][sc + j4 * 4] = *(const float4*)(wp + j4 * 4);
    __syncthreads();
    float acc[4][4] = {};
#pragma unroll 8
    for (int k = 0; k < 128; ++k) {
      float4 fv = *(const float4*)&ft[k][r0];
      float4 wv = *(const float4*)&wt[k][c0];
      FMA16(acc, fv, wv)
    }
    const float4 bv  = *(const float4*)(b2 + cc + c0);
    const float4 gv  = *(const float4*)(gam + cc + c0);
    const float4 btv = *(const float4*)(bet + cc + c0);
#pragma unroll
    for (int i = 0; i < 4; ++i) {
      const int r = r0 + i;
      const size_t row = row0 + r;
      const float mu = mu_s[r], inv = inv_s[r];
      const float4 xv = *(const float4*)(x + row * D_DIM + cc + c0);
      float4 y;
      y.x = fmaf((acc[i][0] + bv.x - mu) * inv, gv.x, btv.x) + xv.x;
      y.y = fmaf((acc[i][1] + bv.y - mu) * inv, gv.y, btv.y) + xv.y;
      y.z = fmaf((acc[i][2] + bv.z - mu) * inv, gv.z, btv.z) + xv.z;
      y.w = fmaf((acc[i][3] + bv.w - mu) * inv, gv.w, btv.w) + xv.w;
      *(float4*)(out + row * D_DIM + cc + c0) = y;
    }
  }
}

extern "C" void kernel_launch(void* const* d_in, const int* in_sizes, int n_in,
                              void* d_out, int out_size, void* d_ws, size_t ws_size,
                              hipStream_t stream) {
  const float* x   = (const float*)d_in[0];
  const float* W1  = (const float*)d_in[1];
  const float* b1  = (const float*)d_in[2];
  const float* W2  = (const float*)d_in[3];
  const float* b2  = (const float*)d_in[4];
  const float* gam = (const float*)d_in[5];
  const float* bet = (const float*)d_in[6];
  float* out = (float*)d_out;
  float* ws  = (float*)d_ws;
  float* feats = ws + OFF_FEATS;
  float* G     = ws + OFF_G;
  float* gpart = ws + OFF_GPART;
  float* wbar  = ws + OFF_WBAR;
  float* hbv   = ws + OFF_HB;
  float* scal  = ws + OFF_SCAL;

  hipLaunchKernelGGL(k0a, dim3(64), dim3(256), 0, stream, W2, gpart);
  hipLaunchKernelGGL(k0b, dim3(64), dim3(256), 0, stream, gpart, G);
  hipLaunchKernelGGL(k0c, dim3(129), dim3(256), 0, stream, W2, b2, wbar, hbv, scal);
  hipLaunchKernelGGL(k1, dim3(B_ROWS / 64), dim3(256), 0, stream, x, W1, b1, feats);
  hipLaunchKernelGGL(k2, dim3(B_ROWS / 64), dim3(256), 0, stream, feats, W2, b2,
                     gam, bet, x, G, wbar, hbv, scal, out);
}